// Round 5
// baseline (38.495 us; speedup 1.0000x reference)
//
#include <hip/hip_runtime.h>
#include <hip/hip_bf16.h>

// SymmetricTransitionDown fused, v3: B=4, N=16384, C=64, O=64, R=8, STRIDE=4.
// 1024 blocks x 64 output rows (+16 halo each side = 96 LDS rows), 16 points,
// 256 threads (4 waves). LDS 32256 B -> up to 4 blocks/CU.
// v3 changes vs v2: launch_bounds min-waves 4->3 (v2's 4 clamped VGPR to 64 and
// spilled 64 dwords/thread -> 64 MB scratch write-back); weight staging lane
// mapping col-major -> k-major (contiguous LDS writes, no 8-way conflicts).
#define NPTS   16384
#define NMASK  16383
#define EPSV   1e-5f
#define OUTOFF 32768            // points_out = 4*4096*2 floats, outputs follow

typedef __attribute__((ext_vector_type(8))) short short8_t;
typedef __attribute__((ext_vector_type(4))) short short4_t;
typedef __attribute__((ext_vector_type(4))) float f32x4;

static __device__ __forceinline__ short f2bf(float x) {
    union { __hip_bfloat16 b; short s; } u; u.b = __float2bfloat16(x); return u.s;
}
static __device__ __forceinline__ float bf2f(short s) {
    union { float f; unsigned u; } v; v.u = ((unsigned)(unsigned short)s) << 16; return v.f;
}

__global__ __launch_bounds__(256, 3) void fused_std_kernel(
    const float* __restrict__ points,
    const float* __restrict__ features,
    const float* __restrict__ w1,
    const float* __restrict__ bn1_gamma, const float* __restrict__ bn1_beta,
    const float* __restrict__ bn1_mean,  const float* __restrict__ bn1_var,
    const float* __restrict__ w2,
    const float* __restrict__ w3,
    const float* __restrict__ bn2_gamma, const float* __restrict__ bn2_beta,
    const float* __restrict__ bn2_mean,  const float* __restrict__ bn2_var,
    float* __restrict__ d_out)
{
    // LDS: 16384 (w) + 12288 (X) + 768 (pts) + 1792 (consts) + 1024 (ebuf)
    //    = 32256 B.
    __shared__ __align__(16) short wlds[8192];      // W^T bf16 [mat][col][k], swizzled
    __shared__ __align__(16) short xlds[96 * 64];   // G' then y, bf16, slot^=(row&7)
    __shared__ __align__(16) float ptsl[96 * 2];
    __shared__ float cP[64], cQ[64], cW2[64], cS1[64], cB1[64], cS2[64], cB2[64];
    __shared__ __align__(16) float ebuf[16][16];    // raw scores [point][neighbor]

    const int tid = threadIdx.x;
    const int wv  = tid >> 6, l = tid & 63;
    const int r   = l & 15,  kg = l >> 4;
    const int bi  = blockIdx.x >> 8;                // batch 0..3
    const int n0  = (blockIdx.x & 255) * 64;        // first output row in batch
    const int base = bi * NPTS;

    // ---- issue this wave's feature loads FIRST (hide HBM latency) ----
    struct TF { float4 a, b, c, d; };
    auto loadTile = [&](int ti) {
        const int gr = base + ((n0 - 16 + ti * 16 + r) & NMASK);
        const float* fp = features + (size_t)gr * 64 + kg * 8;
        TF t;
        t.a = *(const float4*)(fp);
        t.b = *(const float4*)(fp + 4);
        t.c = *(const float4*)(fp + 32);
        t.d = *(const float4*)(fp + 36);
        return t;
    };
    TF Ta = loadTile(wv);
    TF Tb;
    if (wv < 2) Tb = loadTile(4 + wv);

    // ---- stage weights: lane = k (contiguous LDS span, conflict-free) ----
    for (int e = tid; e < 8192; e += 256) {
        const int mat = e >> 12, idx = e & 4095;
        const int k = idx & 63, col = (idx >> 6) & 63;
        const float v = mat ? w3[k * 64 + col] : w1[(2 + k) * 64 + col];
        const int byte = mat * 8192 + col * 128 + ((k * 2) ^ ((col & 7) << 4));
        *(short*)((char*)wlds + byte) = f2bf(v);
    }
    if (tid < 64) {
        const float s1 = bn1_gamma[tid] * rsqrtf(bn1_var[tid] + EPSV);
        cS1[tid] = s1;
        cB1[tid] = bn1_beta[tid] - bn1_mean[tid] * s1;
        cP[tid]  = s1 * w1[tid];
        cQ[tid]  = s1 * w1[64 + tid];
        cW2[tid] = w2[tid];
        const float s2 = bn2_gamma[tid] * rsqrtf(bn2_var[tid] + EPSV);
        cS2[tid] = s2;
        cB2[tid] = bn2_beta[tid] - bn2_mean[tid] * s2;
    }
    for (int t = tid; t < 96; t += 256) {
        const int gr = base + ((n0 - 16 + t) & NMASK);
        *(float2*)&ptsl[t * 2] = *(const float2*)&points[(size_t)gr * 2];
    }
    __syncthreads();

    // ---- phase 1: per tile, 16 MFMAs -> G'(bf16)->LDS, y(bf16)->VGPR cache ----
    auto mfma_tile = [&](const TF& t, int ti, short4_t* yc) {
        short8_t f0, f1;
        f0[0]=f2bf(t.a.x); f0[1]=f2bf(t.a.y); f0[2]=f2bf(t.a.z); f0[3]=f2bf(t.a.w);
        f0[4]=f2bf(t.b.x); f0[5]=f2bf(t.b.y); f0[6]=f2bf(t.b.z); f0[7]=f2bf(t.b.w);
        f1[0]=f2bf(t.c.x); f1[1]=f2bf(t.c.y); f1[2]=f2bf(t.c.z); f1[3]=f2bf(t.c.w);
        f1[4]=f2bf(t.d.x); f1[5]=f2bf(t.d.y); f1[6]=f2bf(t.d.z); f1[7]=f2bf(t.d.w);
        const f32x4 z = {0.f, 0.f, 0.f, 0.f};
        f32x4 acc0[4] = {z, z, z, z}, acc1[4] = {z, z, z, z};
        #pragma unroll
        for (int tt = 0; tt < 4; ++tt) {
            const int col = 16 * tt + r;
            #pragma unroll
            for (int s = 0; s < 2; ++s) {
                const int wb = col * 128 + ((s * 64 + kg * 16) ^ ((r & 7) << 4));
                const short8_t wa = *(const short8_t*)((const char*)wlds + wb);
                acc0[tt] = __builtin_amdgcn_mfma_f32_16x16x32_bf16(wa, s ? f1 : f0, acc0[tt], 0, 0, 0);
                const short8_t wc = *(const short8_t*)((const char*)wlds + 8192 + wb);
                acc1[tt] = __builtin_amdgcn_mfma_f32_16x16x32_bf16(wc, s ? f1 : f0, acc1[tt], 0, 0, 0);
            }
        }
        const int row = ti * 16 + r;   // D: col=l&15 -> row, row=(l>>4)*4+j -> channel
        #pragma unroll
        for (int tt = 0; tt < 4; ++tt) {
            const int c0 = 16 * tt + kg * 4;
            short4_t gq, yq;
            #pragma unroll
            for (int j = 0; j < 4; ++j) {
                gq[j] = f2bf(fmaf(acc0[tt][j], cS1[c0 + j], cB1[c0 + j]));
                yq[j] = f2bf(fmaxf(fmaf(acc1[tt][j], cS2[c0 + j], cB2[c0 + j]), 0.0f));
            }
            const int byte = row * 128 +
                (((2 * tt + (kg >> 1)) ^ (row & 7)) << 4) + ((kg & 1) << 3);
            *(short4_t*)((char*)xlds + byte) = gq;
            yc[tt] = yq;
        }
    };
    short4_t yA[4], yB[4];
    mfma_tile(Ta, wv, yA);
    if (wv < 2) mfma_tile(Tb, 4 + wv, yB);
    __syncthreads();

    // ---- phase 2a: scores. lane = (neighbor knb=r, channel-group kg). ----
    const int offk = (r < 8) ? r - 8 : r - 7;            // [-8..-1, 1..8]
    const f32x4 P0a = *(const f32x4*)&cP[kg * 8],      P0b = *(const f32x4*)&cP[kg * 8 + 4];
    const f32x4 P1a = *(const f32x4*)&cP[32 + kg * 8], P1b = *(const f32x4*)&cP[32 + kg * 8 + 4];
    const f32x4 Q0a = *(const f32x4*)&cQ[kg * 8],      Q0b = *(const f32x4*)&cQ[kg * 8 + 4];
    const f32x4 Q1a = *(const f32x4*)&cQ[32 + kg * 8], Q1b = *(const f32x4*)&cQ[32 + kg * 8 + 4];
    const f32x4 Wa  = *(const f32x4*)&cW2[kg * 8],     Wb  = *(const f32x4*)&cW2[kg * 8 + 4];
    const f32x4 Wc  = *(const f32x4*)&cW2[32 + kg * 8],Wd  = *(const f32x4*)&cW2[32 + kg * 8 + 4];

    #pragma unroll 1
    for (int i = 0; i < 4; ++i) {
        const int p = wv * 4 + i;
        const int crow = 16 + 4 * p;
        const int nrow = crow + offk;
        const float2 cpt = *(const float2*)&ptsl[crow * 2];
        const float2 npt = *(const float2*)&ptsl[nrow * 2];
        const float tx = npt.x - cpt.x, ty = npt.y - cpt.y;
        const short8_t g0 = *(const short8_t*)((const char*)xlds +
            nrow * 128 + ((kg ^ (nrow & 7)) << 4));
        const short8_t g1 = *(const short8_t*)((const char*)xlds +
            nrow * 128 + (((4 + kg) ^ (nrow & 7)) << 4));
        float s = 0.0f;
        #pragma unroll
        for (int e = 0; e < 4; ++e) {
            s = fmaf(fmaxf(bf2f(g0[e])     + tx * P0a[e] + ty * Q0a[e], 0.f), Wa[e], s);
            s = fmaf(fmaxf(bf2f(g0[e + 4]) + tx * P0b[e] + ty * Q0b[e], 0.f), Wb[e], s);
            s = fmaf(fmaxf(bf2f(g1[e])     + tx * P1a[e] + ty * Q1a[e], 0.f), Wc[e], s);
            s = fmaf(fmaxf(bf2f(g1[e + 4]) + tx * P1b[e] + ty * Q1b[e], 0.f), Wd[e], s);
        }
        s += __shfl_xor(s, 16);          // reduce across the 4 channel-groups
        s += __shfl_xor(s, 32);
        if (l < 16) ebuf[p][l] = s;      // lane l holds neighbor l's score
    }
    __syncthreads();                     // all G' reads done

    // ---- phase 1b: overwrite X with cached y ----
    {
        const int rowA = wv * 16 + r;
        #pragma unroll
        for (int tt = 0; tt < 4; ++tt) {
            const int byte = rowA * 128 +
                (((2 * tt + (kg >> 1)) ^ (rowA & 7)) << 4) + ((kg & 1) << 3);
            *(short4_t*)((char*)xlds + byte) = yA[tt];
        }
        if (wv < 2) {
            const int rowB = (4 + wv) * 16 + r;
            #pragma unroll
            for (int tt = 0; tt < 4; ++tt) {
                const int byte = rowB * 128 +
                    (((2 * tt + (kg >> 1)) ^ (rowB & 7)) << 4) + ((kg & 1) << 3);
                *(short4_t*)((char*)xlds + byte) = yB[tt];
            }
        }
    }
    __syncthreads();

    // ---- phase 2b: softmax + weighted y sum. lane = output channel. ----
    #pragma unroll 1
    for (int i = 0; i < 4; ++i) {
        const int p = wv * 4 + i;
        const int crow = 16 + 4 * p;
        const f32x4 sA = *(const f32x4*)&ebuf[p][0];     // broadcast reads
        const f32x4 sB = *(const f32x4*)&ebuf[p][4];
        const f32x4 sC = *(const f32x4*)&ebuf[p][8];
        const f32x4 sD = *(const f32x4*)&ebuf[p][12];
        float mx = fmaxf(fmaxf(fmaxf(sA[0], sA[1]), fmaxf(sA[2], sA[3])),
                   fmaxf(fmaxf(sB[0], sB[1]), fmaxf(sB[2], sB[3])));
        mx = fmaxf(mx, fmaxf(fmaxf(fmaxf(sC[0], sC[1]), fmaxf(sC[2], sC[3])),
                              fmaxf(fmaxf(sD[0], sD[1]), fmaxf(sD[2], sD[3]))));
        float se = 0.0f, o = 0.0f;
        #pragma unroll
        for (int k = 0; k < 16; ++k) {
            const float sck = (k < 4) ? sA[k] : (k < 8) ? sB[k - 4]
                             : (k < 12) ? sC[k - 8] : sD[k - 12];
            const float ek = __expf(sck - mx);
            se += ek;
            const int rk = crow + ((k < 8) ? k - 8 : k - 7);
            const short yb = *(const short*)((const char*)xlds +
                rk * 128 + (((l >> 3) ^ (rk & 7)) << 4) + ((l & 7) << 1));
            o = fmaf(ek, bf2f(yb), o);
        }
        o /= se;
        const int pl = ((blockIdx.x & 255) << 4) + p;
        d_out[OUTOFF + ((size_t)bi * 4096 + pl) * 64 + l] = o;
        if (l < 2)
            d_out[((size_t)bi * 4096 + pl) * 2 + l] = ptsl[crow * 2 + l];
    }
}

// ---------------------------------------------------------------------------
extern "C" void kernel_launch(void* const* d_in, const int* in_sizes, int n_in,
                              void* d_out, int out_size, void* d_ws, size_t ws_size,
                              hipStream_t stream)
{
    const float* points    = (const float*)d_in[0];
    const float* features  = (const float*)d_in[1];
    const float* w1        = (const float*)d_in[2];
    const float* bn1_gamma = (const float*)d_in[3];
    const float* bn1_beta  = (const float*)d_in[4];
    const float* bn1_mean  = (const float*)d_in[5];
    const float* bn1_var   = (const float*)d_in[6];
    const float* w2        = (const float*)d_in[7];
    // d_in[8] = b2: shift-invariant under softmax, intentionally unused
    const float* w3        = (const float*)d_in[9];
    const float* bn2_gamma = (const float*)d_in[10];
    const float* bn2_beta  = (const float*)d_in[11];
    const float* bn2_mean  = (const float*)d_in[12];
    const float* bn2_var   = (const float*)d_in[13];

    fused_std_kernel<<<1024, 256, 0, stream>>>(
        points, features, w1, bn1_gamma, bn1_beta, bn1_mean, bn1_var,
        w2, w3, bn2_gamma, bn2_beta, bn2_mean, bn2_var, (float*)d_out);
}

// Round 6
// 29.085 us; speedup vs baseline: 1.3235x; 1.3235x over previous
//
#include <hip/hip_runtime.h>
#include <hip/hip_bf16.h>

// SymmetricTransitionDown fused, v4: B=4, N=16384, C=64, O=64, R=8, STRIDE=4.
// Prep kernel (1 block) builds the swizzled bf16 weight image (16 KB) + fused
// BN constants (1792 B) in d_ws once; the fused kernel (1024 blocks x 64 output
// rows, +16 halo each side = 96 LDS rows, 256 threads) block-copies them with
// coalesced vector loads instead of 8192 scattered scalar loads per block
// (the measured R5 prologue bottleneck).
#define NPTS   16384
#define NMASK  16383
#define EPSV   1e-5f
#define OUTOFF 32768            // points_out = 4*4096*2 floats, outputs follow

typedef __attribute__((ext_vector_type(8))) short short8_t;
typedef __attribute__((ext_vector_type(4))) short short4_t;
typedef __attribute__((ext_vector_type(4))) float f32x4;

static __device__ __forceinline__ short f2bf(float x) {
    union { __hip_bfloat16 b; short s; } u; u.b = __float2bfloat16(x); return u.s;
}
static __device__ __forceinline__ float bf2f(short s) {
    union { float f; unsigned u; } v; v.u = ((unsigned)(unsigned short)s) << 16; return v.f;
}

// ---------------------------------------------------------------------------
// Prep: d_ws[0..16384) = swizzled bf16 W image; d_ws[16384..18176) = constants
// packed as 7 x 64 floats: cP, cQ, cW2, cS1, cB1, cS2, cB2.
// ---------------------------------------------------------------------------
__global__ __launch_bounds__(256) void prep_kernel(
    const float* __restrict__ w1,
    const float* __restrict__ bn1_gamma, const float* __restrict__ bn1_beta,
    const float* __restrict__ bn1_mean,  const float* __restrict__ bn1_var,
    const float* __restrict__ w2,
    const float* __restrict__ w3,
    const float* __restrict__ bn2_gamma, const float* __restrict__ bn2_beta,
    const float* __restrict__ bn2_mean,  const float* __restrict__ bn2_var,
    void* __restrict__ d_ws)
{
    const int tid = threadIdx.x;
    char* wimg = (char*)d_ws;
    for (int e = tid; e < 8192; e += 256) {
        const int mat = e >> 12, idx = e & 4095;
        const int k = idx & 63, col = (idx >> 6) & 63;
        const float v = mat ? w3[k * 64 + col] : w1[(2 + k) * 64 + col];
        const int byte = mat * 8192 + col * 128 + ((k * 2) ^ ((col & 7) << 4));
        *(short*)(wimg + byte) = f2bf(v);
    }
    float* cst = (float*)(wimg + 16384);
    if (tid < 64) {
        const float s1 = bn1_gamma[tid] * rsqrtf(bn1_var[tid] + EPSV);
        cst[tid]       = s1 * w1[tid];                       // cP
        cst[64 + tid]  = s1 * w1[64 + tid];                  // cQ
        cst[128 + tid] = w2[tid];                            // cW2
        cst[192 + tid] = s1;                                 // cS1
        cst[256 + tid] = bn1_beta[tid] - bn1_mean[tid] * s1; // cB1
        const float s2 = bn2_gamma[tid] * rsqrtf(bn2_var[tid] + EPSV);
        cst[320 + tid] = s2;                                 // cS2
        cst[384 + tid] = bn2_beta[tid] - bn2_mean[tid] * s2; // cB2
    }
}

// ---------------------------------------------------------------------------
__global__ __launch_bounds__(256, 3) void fused_std_kernel(
    const float* __restrict__ points,
    const float* __restrict__ features,
    const void* __restrict__ d_wsv,
    float* __restrict__ d_out)
{
    // LDS: 16384 (w) + 12288 (X) + 768 (pts) + 1792 (consts) + 1024 (ebuf)
    //    = 32256 B -> 4 blocks/CU (grid-limited at 1024 blocks).
    __shared__ __align__(16) short wlds[8192];      // W^T bf16 [mat][col][k], swizzled
    __shared__ __align__(16) short xlds[96 * 64];   // G' then y, bf16, slot^=(row&7)
    __shared__ __align__(16) float ptsl[96 * 2];
    __shared__ __align__(16) float cst[448];        // cP cQ cW2 cS1 cB1 cS2 cB2
    __shared__ __align__(16) float ebuf[16][16];    // raw scores [point][neighbor]

    const float* cP  = cst;
    const float* cQ  = cst + 64;
    const float* cW2 = cst + 128;
    const float* cS1 = cst + 192;
    const float* cB1 = cst + 256;
    const float* cS2 = cst + 320;
    const float* cB2 = cst + 384;

    const int tid = threadIdx.x;
    const int wv  = tid >> 6, l = tid & 63;
    const int r   = l & 15,  kg = l >> 4;
    const int bi  = blockIdx.x >> 8;                // batch 0..3
    const int n0  = (blockIdx.x & 255) * 64;        // first output row in batch
    const int base = bi * NPTS;

    // ---- issue this wave's feature loads FIRST (hide HBM latency) ----
    struct TF { float4 a, b, c, d; };
    auto loadTile = [&](int ti) {
        const int gr = base + ((n0 - 16 + ti * 16 + r) & NMASK);
        const float* fp = features + (size_t)gr * 64 + kg * 8;
        TF t;
        t.a = *(const float4*)(fp);
        t.b = *(const float4*)(fp + 4);
        t.c = *(const float4*)(fp + 32);
        t.d = *(const float4*)(fp + 36);
        return t;
    };
    TF Ta = loadTile(wv);
    TF Tb;
    if (wv < 2) Tb = loadTile(4 + wv);

    // ---- block-copy precomputed weight image + constants (coalesced) ----
    {
        const short8_t* wsrc = (const short8_t*)d_wsv;      // 1024 x 16 B
        short8_t* wdst = (short8_t*)wlds;
        #pragma unroll
        for (int i = 0; i < 4; ++i)
            wdst[tid + 256 * i] = wsrc[tid + 256 * i];
        if (tid < 112)
            ((f32x4*)cst)[tid] = ((const f32x4*)((const char*)d_wsv + 16384))[tid];
    }
    for (int t = tid; t < 96; t += 256) {
        const int gr = base + ((n0 - 16 + t) & NMASK);
        *(float2*)&ptsl[t * 2] = *(const float2*)&points[(size_t)gr * 2];
    }
    __syncthreads();

    // ---- phase 1: per tile, 16 MFMAs -> G'(bf16)->LDS, y(bf16)->VGPR cache ----
    auto mfma_tile = [&](const TF& t, int ti, short4_t* yc) {
        short8_t f0, f1;
        f0[0]=f2bf(t.a.x); f0[1]=f2bf(t.a.y); f0[2]=f2bf(t.a.z); f0[3]=f2bf(t.a.w);
        f0[4]=f2bf(t.b.x); f0[5]=f2bf(t.b.y); f0[6]=f2bf(t.b.z); f0[7]=f2bf(t.b.w);
        f1[0]=f2bf(t.c.x); f1[1]=f2bf(t.c.y); f1[2]=f2bf(t.c.z); f1[3]=f2bf(t.c.w);
        f1[4]=f2bf(t.d.x); f1[5]=f2bf(t.d.y); f1[6]=f2bf(t.d.z); f1[7]=f2bf(t.d.w);
        const f32x4 z = {0.f, 0.f, 0.f, 0.f};
        f32x4 acc0[4] = {z, z, z, z}, acc1[4] = {z, z, z, z};
        #pragma unroll
        for (int tt = 0; tt < 4; ++tt) {
            const int col = 16 * tt + r;
            #pragma unroll
            for (int s = 0; s < 2; ++s) {
                const int wb = col * 128 + ((s * 64 + kg * 16) ^ ((r & 7) << 4));
                const short8_t wa = *(const short8_t*)((const char*)wlds + wb);
                acc0[tt] = __builtin_amdgcn_mfma_f32_16x16x32_bf16(wa, s ? f1 : f0, acc0[tt], 0, 0, 0);
                const short8_t wc = *(const short8_t*)((const char*)wlds + 8192 + wb);
                acc1[tt] = __builtin_amdgcn_mfma_f32_16x16x32_bf16(wc, s ? f1 : f0, acc1[tt], 0, 0, 0);
            }
        }
        const int row = ti * 16 + r;   // D: col=l&15 -> row, row=(l>>4)*4+j -> channel
        #pragma unroll
        for (int tt = 0; tt < 4; ++tt) {
            const int c0 = 16 * tt + kg * 4;
            short4_t gq, yq;
            #pragma unroll
            for (int j = 0; j < 4; ++j) {
                gq[j] = f2bf(fmaf(acc0[tt][j], cS1[c0 + j], cB1[c0 + j]));
                yq[j] = f2bf(fmaxf(fmaf(acc1[tt][j], cS2[c0 + j], cB2[c0 + j]), 0.0f));
            }
            const int byte = row * 128 +
                (((2 * tt + (kg >> 1)) ^ (row & 7)) << 4) + ((kg & 1) << 3);
            *(short4_t*)((char*)xlds + byte) = gq;
            yc[tt] = yq;
        }
    };
    short4_t yA[4], yB[4];
    mfma_tile(Ta, wv, yA);
    if (wv < 2) mfma_tile(Tb, 4 + wv, yB);
    __syncthreads();

    // ---- phase 2a: scores. lane = (neighbor knb=r, channel-group kg). ----
    const int offk = (r < 8) ? r - 8 : r - 7;            // [-8..-1, 1..8]
    const f32x4 P0a = *(const f32x4*)&cP[kg * 8],      P0b = *(const f32x4*)&cP[kg * 8 + 4];
    const f32x4 P1a = *(const f32x4*)&cP[32 + kg * 8], P1b = *(const f32x4*)&cP[32 + kg * 8 + 4];
    const f32x4 Q0a = *(const f32x4*)&cQ[kg * 8],      Q0b = *(const f32x4*)&cQ[kg * 8 + 4];
    const f32x4 Q1a = *(const f32x4*)&cQ[32 + kg * 8], Q1b = *(const f32x4*)&cQ[32 + kg * 8 + 4];
    const f32x4 Wa  = *(const f32x4*)&cW2[kg * 8],     Wb  = *(const f32x4*)&cW2[kg * 8 + 4];
    const f32x4 Wc  = *(const f32x4*)&cW2[32 + kg * 8],Wd  = *(const f32x4*)&cW2[32 + kg * 8 + 4];

    #pragma unroll 1
    for (int i = 0; i < 4; ++i) {
        const int p = wv * 4 + i;
        const int crow = 16 + 4 * p;
        const int nrow = crow + offk;
        const float2 cpt = *(const float2*)&ptsl[crow * 2];
        const float2 npt = *(const float2*)&ptsl[nrow * 2];
        const float tx = npt.x - cpt.x, ty = npt.y - cpt.y;
        const short8_t g0 = *(const short8_t*)((const char*)xlds +
            nrow * 128 + ((kg ^ (nrow & 7)) << 4));
        const short8_t g1 = *(const short8_t*)((const char*)xlds +
            nrow * 128 + (((4 + kg) ^ (nrow & 7)) << 4));
        float s = 0.0f;
        #pragma unroll
        for (int e = 0; e < 4; ++e) {
            s = fmaf(fmaxf(bf2f(g0[e])     + tx * P0a[e] + ty * Q0a[e], 0.f), Wa[e], s);
            s = fmaf(fmaxf(bf2f(g0[e + 4]) + tx * P0b[e] + ty * Q0b[e], 0.f), Wb[e], s);
            s = fmaf(fmaxf(bf2f(g1[e])     + tx * P1a[e] + ty * Q1a[e], 0.f), Wc[e], s);
            s = fmaf(fmaxf(bf2f(g1[e + 4]) + tx * P1b[e] + ty * Q1b[e], 0.f), Wd[e], s);
        }
        s += __shfl_xor(s, 16);          // reduce across the 4 channel-groups
        s += __shfl_xor(s, 32);
        if (l < 16) ebuf[p][l] = s;      // lane l holds neighbor l's score
    }
    __syncthreads();                     // all G' reads done

    // ---- phase 1b: overwrite X with cached y ----
    {
        const int rowA = wv * 16 + r;
        #pragma unroll
        for (int tt = 0; tt < 4; ++tt) {
            const int byte = rowA * 128 +
                (((2 * tt + (kg >> 1)) ^ (rowA & 7)) << 4) + ((kg & 1) << 3);
            *(short4_t*)((char*)xlds + byte) = yA[tt];
        }
        if (wv < 2) {
            const int rowB = (4 + wv) * 16 + r;
            #pragma unroll
            for (int tt = 0; tt < 4; ++tt) {
                const int byte = rowB * 128 +
                    (((2 * tt + (kg >> 1)) ^ (rowB & 7)) << 4) + ((kg & 1) << 3);
                *(short4_t*)((char*)xlds + byte) = yB[tt];
            }
        }
    }
    __syncthreads();

    // ---- phase 2b: softmax + weighted y sum. lane = output channel. ----
    #pragma unroll 1
    for (int i = 0; i < 4; ++i) {
        const int p = wv * 4 + i;
        const int crow = 16 + 4 * p;
        const f32x4 sA = *(const f32x4*)&ebuf[p][0];     // broadcast reads
        const f32x4 sB = *(const f32x4*)&ebuf[p][4];
        const f32x4 sC = *(const f32x4*)&ebuf[p][8];
        const f32x4 sD = *(const f32x4*)&ebuf[p][12];
        float mx = fmaxf(fmaxf(fmaxf(sA[0], sA[1]), fmaxf(sA[2], sA[3])),
                   fmaxf(fmaxf(sB[0], sB[1]), fmaxf(sB[2], sB[3])));
        mx = fmaxf(mx, fmaxf(fmaxf(fmaxf(sC[0], sC[1]), fmaxf(sC[2], sC[3])),
                              fmaxf(fmaxf(sD[0], sD[1]), fmaxf(sD[2], sD[3]))));
        float se = 0.0f, o = 0.0f;
        #pragma unroll
        for (int k = 0; k < 16; ++k) {
            const float sck = (k < 4) ? sA[k] : (k < 8) ? sB[k - 4]
                             : (k < 12) ? sC[k - 8] : sD[k - 12];
            const float ek = __expf(sck - mx);
            se += ek;
            const int rk = crow + ((k < 8) ? k - 8 : k - 7);
            const short yb = *(const short*)((const char*)xlds +
                rk * 128 + (((l >> 3) ^ (rk & 7)) << 4) + ((l & 7) << 1));
            o = fmaf(ek, bf2f(yb), o);
        }
        o /= se;
        const int pl = ((blockIdx.x & 255) << 4) + p;
        d_out[OUTOFF + ((size_t)bi * 4096 + pl) * 64 + l] = o;
        if (l < 2)
            d_out[((size_t)bi * 4096 + pl) * 2 + l] = ptsl[crow * 2 + l];
    }
}

// ---------------------------------------------------------------------------
extern "C" void kernel_launch(void* const* d_in, const int* in_sizes, int n_in,
                              void* d_out, int out_size, void* d_ws, size_t ws_size,
                              hipStream_t stream)
{
    const float* points    = (const float*)d_in[0];
    const float* features  = (const float*)d_in[1];
    const float* w1        = (const float*)d_in[2];
    const float* bn1_gamma = (const float*)d_in[3];
    const float* bn1_beta  = (const float*)d_in[4];
    const float* bn1_mean  = (const float*)d_in[5];
    const float* bn1_var   = (const float*)d_in[6];
    const float* w2        = (const float*)d_in[7];
    // d_in[8] = b2: shift-invariant under softmax, intentionally unused
    const float* w3        = (const float*)d_in[9];
    const float* bn2_gamma = (const float*)d_in[10];
    const float* bn2_beta  = (const float*)d_in[11];
    const float* bn2_mean  = (const float*)d_in[12];
    const float* bn2_var   = (const float*)d_in[13];

    prep_kernel<<<1, 256, 0, stream>>>(
        w1, bn1_gamma, bn1_beta, bn1_mean, bn1_var, w2,
        w3, bn2_gamma, bn2_beta, bn2_mean, bn2_var, d_ws);

    fused_std_kernel<<<1024, 256, 0, stream>>>(
        points, features, d_ws, (float*)d_out);
}

// Round 7
// 25.408 us; speedup vs baseline: 1.5151x; 1.1447x over previous
//
#include <hip/hip_runtime.h>
#include <hip/hip_bf16.h>

// SymmetricTransitionDown fused, v5: B=4, N=16384, C=64, O=64, R=8, STRIDE=4.
// prep (32 blocks, ~1-2us) builds swizzled bf16 weight image + fused BN
// constants in d_ws. fused (1024 blocks x 64 output rows, +16 halo = 96 LDS
// rows, 256 thr) loads weight FRAGMENTS directly from d_ws into VGPRs (no
// weight LDS, no copy); separate G'/y LDS buffers cut barriers 4 -> 2.
#define NPTS   16384
#define NMASK  16383
#define EPSV   1e-5f
#define OUTOFF 32768            // points_out = 4*4096*2 floats, outputs follow

typedef __attribute__((ext_vector_type(8))) short short8_t;
typedef __attribute__((ext_vector_type(4))) short short4_t;
typedef __attribute__((ext_vector_type(4))) float f32x4;

static __device__ __forceinline__ short f2bf(float x) {
    union { __hip_bfloat16 b; short s; } u; u.b = __float2bfloat16(x); return u.s;
}
static __device__ __forceinline__ float bf2f(short s) {
    union { float f; unsigned u; } v; v.u = ((unsigned)(unsigned short)s) << 16; return v.f;
}

// ---------------------------------------------------------------------------
// Prep: d_ws[0..16384) = swizzled bf16 W image ([mat][col][k], fragment order);
// d_ws[16384..18176) = 7 x 64 floats: cP, cQ, cW2, cS1, cB1, cS2, cB2.
// 32 blocks x 256 threads, one element each; coalesced reads.
// ---------------------------------------------------------------------------
__global__ __launch_bounds__(256) void prep_kernel(
    const float* __restrict__ w1,
    const float* __restrict__ bn1_gamma, const float* __restrict__ bn1_beta,
    const float* __restrict__ bn1_mean,  const float* __restrict__ bn1_var,
    const float* __restrict__ w2,
    const float* __restrict__ w3,
    const float* __restrict__ bn2_gamma, const float* __restrict__ bn2_beta,
    const float* __restrict__ bn2_mean,  const float* __restrict__ bn2_var,
    void* __restrict__ d_ws)
{
    const int e = blockIdx.x * 256 + threadIdx.x;        // 0..8191
    const int mat = e >> 12, idx = e & 4095;
    const int k = idx >> 6, col = idx & 63;              // lane=col -> coalesced read
    const float v = mat ? w3[k * 64 + col] : w1[(2 + k) * 64 + col];
    const int byte = mat * 8192 + col * 128 + ((k * 2) ^ ((col & 7) << 4));
    *(short*)((char*)d_ws + byte) = f2bf(v);

    if (blockIdx.x == 0 && threadIdx.x < 64) {
        const int t = threadIdx.x;
        float* cst = (float*)((char*)d_ws + 16384);
        const float s1 = bn1_gamma[t] * rsqrtf(bn1_var[t] + EPSV);
        cst[t]       = s1 * w1[t];                       // cP
        cst[64 + t]  = s1 * w1[64 + t];                  // cQ
        cst[128 + t] = w2[t];                            // cW2
        cst[192 + t] = s1;                               // cS1
        cst[256 + t] = bn1_beta[t] - bn1_mean[t] * s1;   // cB1
        const float s2 = bn2_gamma[t] * rsqrtf(bn2_var[t] + EPSV);
        cst[320 + t] = s2;                               // cS2
        cst[384 + t] = bn2_beta[t] - bn2_mean[t] * s2;   // cB2
    }
}

// ---------------------------------------------------------------------------
__global__ __launch_bounds__(256, 3) void fused_std_kernel(
    const float* __restrict__ points,
    const float* __restrict__ features,
    const void* __restrict__ d_wsv,
    float* __restrict__ d_out)
{
    // LDS: 12288 (G') + 12288 (y) + 768 (pts) + 1792 (consts) + 1024 (ebuf)
    //    = 28160 B.
    __shared__ __align__(16) short glds[96 * 64];   // G' bf16, slot^=(row&7)
    __shared__ __align__(16) short ylds[96 * 64];   // y  bf16, same layout
    __shared__ __align__(16) float ptsl[96 * 2];
    __shared__ __align__(16) float cst[448];        // cP cQ cW2 cS1 cB1 cS2 cB2
    __shared__ __align__(16) float ebuf[16][16];    // raw scores [point][neighbor]

    const float* cP  = cst;
    const float* cQ  = cst + 64;
    const float* cW2 = cst + 128;
    const float* cS1 = cst + 192;
    const float* cB1 = cst + 256;
    const float* cS2 = cst + 320;
    const float* cB2 = cst + 384;

    const int tid = threadIdx.x;
    const int wv  = tid >> 6, l = tid & 63;
    const int r   = l & 15,  kg = l >> 4;
    const int bi  = blockIdx.x >> 8;                // batch 0..3
    const int n0  = (blockIdx.x & 255) * 64;        // first output row in batch
    const int base = bi * NPTS;

    // ---- issue this wave's feature loads FIRST (hide HBM latency) ----
    struct TF { float4 a, b, c, d; };
    auto loadTile = [&](int ti) {
        const int gr = base + ((n0 - 16 + ti * 16 + r) & NMASK);
        const float* fp = features + (size_t)gr * 64 + kg * 8;
        TF t;
        t.a = *(const float4*)(fp);
        t.b = *(const float4*)(fp + 4);
        t.c = *(const float4*)(fp + 32);
        t.d = *(const float4*)(fp + 36);
        return t;
    };
    TF Ta = loadTile(wv);
    TF Tb;
    if (wv < 2) Tb = loadTile(4 + wv);

    // ---- weight fragments straight into VGPRs (L1/L2-resident broadcast) ----
    short8_t wf[2][4][2];                           // [mat][col-tile][k-step]
    {
        const char* wbase = (const char*)d_wsv;
        #pragma unroll
        for (int mat = 0; mat < 2; ++mat)
            #pragma unroll
            for (int tt = 0; tt < 4; ++tt)
                #pragma unroll
                for (int s = 0; s < 2; ++s) {
                    const int col = 16 * tt + r;
                    const int wb  = col * 128 + ((s * 64 + kg * 16) ^ ((r & 7) << 4));
                    wf[mat][tt][s] = *(const short8_t*)(wbase + mat * 8192 + wb);
                }
    }

    // ---- stage constants + points ----
    if (tid < 112)
        ((f32x4*)cst)[tid] = ((const f32x4*)((const char*)d_wsv + 16384))[tid];
    for (int t = tid; t < 96; t += 256) {
        const int gr = base + ((n0 - 16 + t) & NMASK);
        *(float2*)&ptsl[t * 2] = *(const float2*)&points[(size_t)gr * 2];
    }
    __syncthreads();

    // ---- phase 1: per tile, 16 MFMAs -> G'(bf16)->LDS, y(bf16)->LDS ----
    auto mfma_tile = [&](const TF& t, int ti) {
        short8_t f0, f1;
        f0[0]=f2bf(t.a.x); f0[1]=f2bf(t.a.y); f0[2]=f2bf(t.a.z); f0[3]=f2bf(t.a.w);
        f0[4]=f2bf(t.b.x); f0[5]=f2bf(t.b.y); f0[6]=f2bf(t.b.z); f0[7]=f2bf(t.b.w);
        f1[0]=f2bf(t.c.x); f1[1]=f2bf(t.c.y); f1[2]=f2bf(t.c.z); f1[3]=f2bf(t.c.w);
        f1[4]=f2bf(t.d.x); f1[5]=f2bf(t.d.y); f1[6]=f2bf(t.d.z); f1[7]=f2bf(t.d.w);
        const f32x4 z = {0.f, 0.f, 0.f, 0.f};
        f32x4 acc0[4] = {z, z, z, z}, acc1[4] = {z, z, z, z};
        #pragma unroll
        for (int tt = 0; tt < 4; ++tt) {
            #pragma unroll
            for (int s = 0; s < 2; ++s) {
                acc0[tt] = __builtin_amdgcn_mfma_f32_16x16x32_bf16(wf[0][tt][s], s ? f1 : f0, acc0[tt], 0, 0, 0);
                acc1[tt] = __builtin_amdgcn_mfma_f32_16x16x32_bf16(wf[1][tt][s], s ? f1 : f0, acc1[tt], 0, 0, 0);
            }
        }
        const int row = ti * 16 + r;   // D: col=l&15 -> row, row=(l>>4)*4+j -> channel
        #pragma unroll
        for (int tt = 0; tt < 4; ++tt) {
            const int c0 = 16 * tt + kg * 4;
            short4_t gq, yq;
            #pragma unroll
            for (int j = 0; j < 4; ++j) {
                gq[j] = f2bf(fmaf(acc0[tt][j], cS1[c0 + j], cB1[c0 + j]));
                yq[j] = f2bf(fmaxf(fmaf(acc1[tt][j], cS2[c0 + j], cB2[c0 + j]), 0.0f));
            }
            const int byte = row * 128 +
                (((2 * tt + (kg >> 1)) ^ (row & 7)) << 4) + ((kg & 1) << 3);
            *(short4_t*)((char*)glds + byte) = gq;
            *(short4_t*)((char*)ylds + byte) = yq;
        }
    };
    mfma_tile(Ta, wv);
    if (wv < 2) mfma_tile(Tb, 4 + wv);
    __syncthreads();

    // ---- phase 2a: scores. lane = (neighbor knb=r, channel-group kg). ----
    const int offk = (r < 8) ? r - 8 : r - 7;            // [-8..-1, 1..8]
    const f32x4 P0a = *(const f32x4*)&cP[kg * 8],      P0b = *(const f32x4*)&cP[kg * 8 + 4];
    const f32x4 P1a = *(const f32x4*)&cP[32 + kg * 8], P1b = *(const f32x4*)&cP[32 + kg * 8 + 4];
    const f32x4 Q0a = *(const f32x4*)&cQ[kg * 8],      Q0b = *(const f32x4*)&cQ[kg * 8 + 4];
    const f32x4 Q1a = *(const f32x4*)&cQ[32 + kg * 8], Q1b = *(const f32x4*)&cQ[32 + kg * 8 + 4];
    const f32x4 Wa  = *(const f32x4*)&cW2[kg * 8],     Wb  = *(const f32x4*)&cW2[kg * 8 + 4];
    const f32x4 Wc  = *(const f32x4*)&cW2[32 + kg * 8],Wd  = *(const f32x4*)&cW2[32 + kg * 8 + 4];

    #pragma unroll 1
    for (int i = 0; i < 4; ++i) {
        const int p = wv * 4 + i;
        const int crow = 16 + 4 * p;
        const int nrow = crow + offk;
        const float2 cpt = *(const float2*)&ptsl[crow * 2];
        const float2 npt = *(const float2*)&ptsl[nrow * 2];
        const float tx = npt.x - cpt.x, ty = npt.y - cpt.y;
        const short8_t g0 = *(const short8_t*)((const char*)glds +
            nrow * 128 + ((kg ^ (nrow & 7)) << 4));
        const short8_t g1 = *(const short8_t*)((const char*)glds +
            nrow * 128 + (((4 + kg) ^ (nrow & 7)) << 4));
        float s = 0.0f;
        #pragma unroll
        for (int e = 0; e < 4; ++e) {
            s = fmaf(fmaxf(bf2f(g0[e])     + tx * P0a[e] + ty * Q0a[e], 0.f), Wa[e], s);
            s = fmaf(fmaxf(bf2f(g0[e + 4]) + tx * P0b[e] + ty * Q0b[e], 0.f), Wb[e], s);
            s = fmaf(fmaxf(bf2f(g1[e])     + tx * P1a[e] + ty * Q1a[e], 0.f), Wc[e], s);
            s = fmaf(fmaxf(bf2f(g1[e + 4]) + tx * P1b[e] + ty * Q1b[e], 0.f), Wd[e], s);
        }
        s += __shfl_xor(s, 16);          // reduce across the 4 channel-groups
        s += __shfl_xor(s, 32);
        if (l < 16) ebuf[p][l] = s;      // lane l holds neighbor l's score
    }
    // ebuf is wave-local (wave wv wrote & reads only p = wv*4..wv*4+3):
    // no block barrier needed, just drain LDS and pin ordering (R3-verified).
    asm volatile("s_waitcnt lgkmcnt(0)" ::: "memory");

    // ---- phase 2b: softmax + weighted y sum. lane = output channel. ----
    #pragma unroll 1
    for (int i = 0; i < 4; ++i) {
        const int p = wv * 4 + i;
        const int crow = 16 + 4 * p;
        const f32x4 sA = *(const f32x4*)&ebuf[p][0];     // broadcast reads
        const f32x4 sB = *(const f32x4*)&ebuf[p][4];
        const f32x4 sC = *(const f32x4*)&ebuf[p][8];
        const f32x4 sD = *(const f32x4*)&ebuf[p][12];
        float mx = fmaxf(fmaxf(fmaxf(sA[0], sA[1]), fmaxf(sA[2], sA[3])),
                   fmaxf(fmaxf(sB[0], sB[1]), fmaxf(sB[2], sB[3])));
        mx = fmaxf(mx, fmaxf(fmaxf(fmaxf(sC[0], sC[1]), fmaxf(sC[2], sC[3])),
                              fmaxf(fmaxf(sD[0], sD[1]), fmaxf(sD[2], sD[3]))));
        float se = 0.0f, o = 0.0f;
        #pragma unroll
        for (int k = 0; k < 16; ++k) {
            const float sck = (k < 4) ? sA[k] : (k < 8) ? sB[k - 4]
                             : (k < 12) ? sC[k - 8] : sD[k - 12];
            const float ek = __expf(sck - mx);
            se += ek;
            const int rk = crow + ((k < 8) ? k - 8 : k - 7);
            const short yb = *(const short*)((const char*)ylds +
                rk * 128 + (((l >> 3) ^ (rk & 7)) << 4) + ((l & 7) << 1));
            o = fmaf(ek, bf2f(yb), o);
        }
        o /= se;
        const int pl = ((blockIdx.x & 255) << 4) + p;
        d_out[OUTOFF + ((size_t)bi * 4096 + pl) * 64 + l] = o;
        if (l < 2)
            d_out[((size_t)bi * 4096 + pl) * 2 + l] = ptsl[crow * 2 + l];
    }
}

// ---------------------------------------------------------------------------
extern "C" void kernel_launch(void* const* d_in, const int* in_sizes, int n_in,
                              void* d_out, int out_size, void* d_ws, size_t ws_size,
                              hipStream_t stream)
{
    const float* points    = (const float*)d_in[0];
    const float* features  = (const float*)d_in[1];
    const float* w1        = (const float*)d_in[2];
    const float* bn1_gamma = (const float*)d_in[3];
    const float* bn1_beta  = (const float*)d_in[4];
    const float* bn1_mean  = (const float*)d_in[5];
    const float* bn1_var   = (const float*)d_in[6];
    const float* w2        = (const float*)d_in[7];
    // d_in[8] = b2: shift-invariant under softmax, intentionally unused
    const float* w3        = (const float*)d_in[9];
    const float* bn2_gamma = (const float*)d_in[10];
    const float* bn2_beta  = (const float*)d_in[11];
    const float* bn2_mean  = (const float*)d_in[12];
    const float* bn2_var   = (const float*)d_in[13];

    prep_kernel<<<32, 256, 0, stream>>>(
        w1, bn1_gamma, bn1_beta, bn1_mean, bn1_var, w2,
        w3, bn2_gamma, bn2_beta, bn2_mean, bn2_var, d_ws);

    fused_std_kernel<<<1024, 256, 0, stream>>>(
        points, features, d_ws, (float*)d_out);
}